// Round 1
// baseline (311.689 us; speedup 1.0000x reference)
//
#include <hip/hip_runtime.h>
#include <hip/hip_bf16.h>
#include <cstdint>
#include <cstddef>

typedef __bf16 bf16_t;
typedef bf16_t bf16x8 __attribute__((ext_vector_type(8)));
typedef bf16_t bf16x4 __attribute__((ext_vector_type(4)));
typedef float f32x4 __attribute__((ext_vector_type(4)));

#define BN_EPS 1e-5f

// Async global->LDS, 16B per lane. LDS dest must be wave-uniform base; HW
// writes lane i at base + i*16.
__device__ __forceinline__ void async_load16(const bf16_t* g, bf16_t* lds) {
  __builtin_amdgcn_global_load_lds(
      (__attribute__((address_space(1))) uint32_t*)(g),
      (__attribute__((address_space(3))) uint32_t*)(lds),
      16, 0, 0);
}

// ---- Prep: fold BN + bias into per-column scale/shift -----------------------
__global__ void prep_scales_kernel(const float* g1, const float* be1, const float* m1,
                                   const float* v1, const float* b1,
                                   const float* g2, const float* be2, const float* m2,
                                   const float* v2, const float* b2,
                                   float* s1, float* t1, float* s2, float* t2) {
  int i = blockIdx.x * 256 + threadIdx.x;
  if (i < 1024) {
    float s = g1[i] * rsqrtf(v1[i] + BN_EPS);
    s1[i] = s;
    t1[i] = be1[i] - m1[i] * s + b1[i] * s;  // bn(z+b1) = z*s + t
  }
  if (i < 512) {
    float s = g2[i] * rsqrtf(v2[i] + BN_EPS);
    s2[i] = s;
    t2[i] = be2[i] - m2[i] * s + b2[i] * s;
  }
}

// ---- Prep: W1 (257x1024 f32) -> W1T (1024x256 bf16, K-contig) + last row ----
__global__ void prep_w1t_kernel(const float* __restrict__ W1, bf16_t* __restrict__ W1T,
                                float* __restrict__ w1last) {
  int n = blockIdx.x;    // 0..1023
  int k = threadIdx.x;   // 0..255
  W1T[n * 256 + k] = (bf16_t)W1[k * 1024 + n];
  if (k == 0) w1last[n] = W1[256 * 1024 + n];  // conv-feature row, kept fp32
}

// ---- Prep: W2 (1024x512 f32) -> W2T (512x1024 bf16) -------------------------
__global__ void prep_w2t_kernel(const float* __restrict__ W2, bf16_t* __restrict__ W2T) {
  int n = blockIdx.x;    // 0..511
  int t = threadIdx.x;   // 0..255
#pragma unroll
  for (int i = 0; i < 4; ++i) {
    int k = i * 256 + t;
    W2T[n * 1024 + k] = (bf16_t)W2[k * 512 + n];
  }
}

// ---- Prep: x -> bf16 + conv feature (mean>0) --------------------------------
__global__ void prep_x_kernel(const float* __restrict__ x, bf16_t* __restrict__ xb,
                              float* __restrict__ convf) {
  int lane = threadIdx.x & 63;
  int w = threadIdx.x >> 6;
  int row = blockIdx.x * 4 + w;  // 4 rows per block (one per wave)
  const float4 v = *(const float4*)(x + (size_t)row * 256 + lane * 4);
  float s = v.x + v.y + v.z + v.w;
  bf16x4 o = {(bf16_t)v.x, (bf16_t)v.y, (bf16_t)v.z, (bf16_t)v.w};
  *(bf16x4*)(xb + (size_t)row * 256 + lane * 4) = o;
#pragma unroll
  for (int off = 32; off >= 1; off >>= 1) s += __shfl_down(s, off);
  if (lane == 0) convf[row] = (s > 0.0f) ? 1.0f : 0.0f;  // mean>0 <=> sum>0
}

// ---- Fused GEMM (C = A * BT^T) + epilogue: bn-scale + relu -> bf16 ----------
// A: [M x K] bf16 row-major (K contig).  BT: [N x K] bf16 row-major (K contig).
// 128x128 block tile, 4 waves each 64x64 (4x4 of 16x16x32 MFMA), BK=32.
template <int K, int N, bool LAYER1>
__global__ __launch_bounds__(256) void mlp_gemm_kernel(
    const bf16_t* __restrict__ A, const bf16_t* __restrict__ BT,
    const float* __restrict__ sN, const float* __restrict__ tN,
    const float* __restrict__ convf, const float* __restrict__ w1last,
    bf16_t* __restrict__ out) {
  __shared__ __align__(16) bf16_t As[128 * 32];
  __shared__ __align__(16) bf16_t Bs[128 * 32];

  const int tid = threadIdx.x;
  const int lane = tid & 63;
  const int w = tid >> 6;         // wave 0..3
  const int l15 = lane & 15;
  const int quad = lane >> 4;     // 0..3
  const int wm = (w >> 1) * 64;   // wave row offset in tile
  const int wn = (w & 1) * 64;    // wave col offset in tile
  const int mTile = blockIdx.y * 128;
  const int nTile = blockIdx.x * 128;

  // Staging: wave w covers rows [w*32, w*32+32) of each tile; 2 insts each.
  const int sRow = lane >> 2;         // 0..15
  const int sCol = (lane & 3) * 8;    // k element offset
  const bf16_t* gA = A + (size_t)(mTile + w * 32 + sRow) * K + sCol;
  const bf16_t* gB = BT + (size_t)(nTile + w * 32 + sRow) * K + sCol;
  bf16_t* lA = As + (w * 32) * 32;    // wave-uniform LDS base
  bf16_t* lB = Bs + (w * 32) * 32;

  f32x4 acc[4][4];
#pragma unroll
  for (int i = 0; i < 4; ++i) {
#pragma unroll
    for (int j = 0; j < 4; ++j) {
      f32x4 z = {0.f, 0.f, 0.f, 0.f};
      acc[i][j] = z;
    }
  }

  for (int k0 = 0; k0 < K; k0 += 32) {
    async_load16(gA + k0, lA);
    async_load16(gA + (size_t)16 * K + k0, lA + 16 * 32);
    async_load16(gB + k0, lB);
    async_load16(gB + (size_t)16 * K + k0, lB + 16 * 32);
    __syncthreads();  // compiler drains vmcnt before s_barrier

    bf16x8 af[4], bfr[4];
#pragma unroll
    for (int t = 0; t < 4; ++t) {
      af[t] = *(const bf16x8*)(As + (wm + t * 16 + l15) * 32 + quad * 8);
      bfr[t] = *(const bf16x8*)(Bs + (wn + t * 16 + l15) * 32 + quad * 8);
    }
#pragma unroll
    for (int ti = 0; ti < 4; ++ti) {
#pragma unroll
      for (int tj = 0; tj < 4; ++tj) {
        acc[ti][tj] = __builtin_amdgcn_mfma_f32_16x16x32_bf16(af[ti], bfr[tj], acc[ti][tj], 0, 0, 0);
      }
    }
    __syncthreads();
  }

  // Epilogue. C/D layout: col = lane&15, row = quad*4 + reg.
  float sc[4], tc[4], wl[4];
#pragma unroll
  for (int tj = 0; tj < 4; ++tj) {
    int c = nTile + wn + tj * 16 + l15;
    sc[tj] = sN[c];
    tc[tj] = tN[c];
    if (LAYER1) wl[tj] = w1last[c];
  }
#pragma unroll
  for (int ti = 0; ti < 4; ++ti) {
#pragma unroll
    for (int r = 0; r < 4; ++r) {
      int row = mTile + wm + ti * 16 + quad * 4 + r;
      float cf = LAYER1 ? convf[row] : 0.f;
      size_t base = (size_t)row * N + nTile + wn;
#pragma unroll
      for (int tj = 0; tj < 4; ++tj) {
        float z = acc[ti][tj][r];
        if (LAYER1) z += cf * wl[tj];
        z = z * sc[tj] + tc[tj];
        z = fmaxf(z, 0.f);
        out[base + tj * 16 + l15] = (bf16_t)z;
      }
    }
  }
}

// ---- Output head: dot(h2_row, W3) + b3, sigmoid -----------------------------
__global__ void gemv_out_kernel(const bf16_t* __restrict__ h2, const float* __restrict__ W3,
                                const float* __restrict__ b3, float* __restrict__ out) {
  int lane = threadIdx.x & 63;
  int w = threadIdx.x >> 6;
  int row = blockIdx.x * 4 + w;
  bf16x8 hv = *(const bf16x8*)(h2 + (size_t)row * 512 + lane * 8);
  float4 wa = *(const float4*)(W3 + lane * 8);
  float4 wb = *(const float4*)(W3 + lane * 8 + 4);
  float s = (float)hv[0] * wa.x + (float)hv[1] * wa.y + (float)hv[2] * wa.z + (float)hv[3] * wa.w +
            (float)hv[4] * wb.x + (float)hv[5] * wb.y + (float)hv[6] * wb.z + (float)hv[7] * wb.w;
#pragma unroll
  for (int off = 32; off >= 1; off >>= 1) s += __shfl_down(s, off);
  if (lane == 0) {
    float z = s + b3[0];
    out[row] = 1.0f / (1.0f + expf(-z));
  }
}

extern "C" void kernel_launch(void* const* d_in, const int* in_sizes, int n_in,
                              void* d_out, int out_size, void* d_ws, size_t ws_size,
                              hipStream_t stream) {
  const float* x = (const float*)d_in[0];
  const float* W1 = (const float*)d_in[1];
  const float* b1 = (const float*)d_in[2];
  const float* g1 = (const float*)d_in[3];
  const float* be1 = (const float*)d_in[4];
  const float* m1 = (const float*)d_in[5];
  const float* v1 = (const float*)d_in[6];
  const float* W2 = (const float*)d_in[7];
  const float* b2 = (const float*)d_in[8];
  const float* g2 = (const float*)d_in[9];
  const float* be2 = (const float*)d_in[10];
  const float* m2 = (const float*)d_in[11];
  const float* v2 = (const float*)d_in[12];
  const float* W3 = (const float*)d_in[13];
  const float* b3 = (const float*)d_in[14];
  float* out = (float*)d_out;

  char* p = (char*)d_ws;
  bf16_t* h1 = (bf16_t*)p;    p += (size_t)65536 * 1024 * 2;  // 128 MB
  bf16_t* h2 = (bf16_t*)p;    p += (size_t)65536 * 512 * 2;   // 64 MB
  bf16_t* xb = (bf16_t*)p;    p += (size_t)65536 * 256 * 2;   // 32 MB
  bf16_t* W1T = (bf16_t*)p;   p += (size_t)1024 * 256 * 2;
  bf16_t* W2T = (bf16_t*)p;   p += (size_t)512 * 1024 * 2;
  float* convf = (float*)p;   p += (size_t)65536 * 4;
  float* w1last = (float*)p;  p += 1024 * 4;
  float* s1 = (float*)p;      p += 1024 * 4;
  float* t1 = (float*)p;      p += 1024 * 4;
  float* s2 = (float*)p;      p += 512 * 4;
  float* t2 = (float*)p;      p += 512 * 4;

  prep_scales_kernel<<<4, 256, 0, stream>>>(g1, be1, m1, v1, b1, g2, be2, m2, v2, b2, s1, t1, s2, t2);
  prep_w1t_kernel<<<1024, 256, 0, stream>>>(W1, W1T, w1last);
  prep_w2t_kernel<<<512, 256, 0, stream>>>(W2, W2T);
  prep_x_kernel<<<16384, 256, 0, stream>>>(x, xb, convf);

  mlp_gemm_kernel<256, 1024, true><<<dim3(8, 512), 256, 0, stream>>>(
      xb, W1T, s1, t1, convf, w1last, h1);
  mlp_gemm_kernel<1024, 512, false><<<dim3(4, 512), 256, 0, stream>>>(
      h1, W2T, s2, t2, nullptr, nullptr, h2);

  gemv_out_kernel<<<16384, 256, 0, stream>>>(h2, W3, b3, out);
}